// Round 1
// baseline (916.937 us; speedup 1.0000x reference)
//
#include <hip/hip_runtime.h>
#include <hip/hip_bf16.h>

// relationLoss: 1024 chain-products of 6 generator matrices (256x256),
// Frobenius norm of A-B per relation, mean over 512 relations.
// Strategy: bf16 MFMA (16x16x32), wave-private row slices, no barriers.

#define NG   32
#define DD   256
#define NREL 512

typedef __attribute__((ext_vector_type(8))) short bf16x8;  // 8 bf16 = 4 VGPRs
typedef __attribute__((ext_vector_type(4))) float f32x4;   // 4 f32 acc

// ---------------- prep: fp32 -> bf16 (row-major + transposed), zero partials ----
__global__ void prep_kernel(const float* __restrict__ G,
                            __hip_bfloat16* __restrict__ Gbf,
                            __hip_bfloat16* __restrict__ Gt,
                            float* __restrict__ part)
{
    int idx = blockIdx.x * 256 + threadIdx.x;      // 0 .. 32*256*256-1
    int g   = idx >> 16;
    int rem = idx & 65535;
    int i   = rem >> 8;      // row
    int j   = rem & 255;     // col
    __hip_bfloat16 h = __float2bfloat16(G[idx]);
    Gbf[idx] = h;                                  // row-major
    Gt[(g << 16) + (j << 8) + i] = h;              // transposed: Gt[g][col][row]
    if (idx < NREL) part[idx] = 0.0f;
}

// LDS byte offset with XOR swizzle: row stride is 512B -> without swizzle a
// 16-lane column read (stride 512B) is a full bank conflict. (row&7)<<4 spreads
// rows across eight 16B slots; 16B reads stay 16B-aligned.
__device__ __forceinline__ int lds_off(int row, int col)
{
    return ((row << 9) + (col << 1)) ^ ((row & 7) << 4);
}

// One chain step: M_new(32x256, this wave's rows) = M(afrag) @ G (via Gt).
// MODE 0: write M_new to wave-private LDS (bf16) and reload afrag.
// MODE 1: keep fp32 result in Afin (chain A final step).
// MODE 2: diff vs Afin, accumulate squared Frobenius (chain B final step).
template<int MODE>
__device__ __forceinline__
void chain_step(bf16x8 afrag[2][8], const __hip_bfloat16* __restrict__ Gt_g,
                char* __restrict__ myM, f32x4 Afin[16][2], float& dsq,
                int lr, int lg)
{
#pragma unroll
    for (int j = 0; j < 16; ++j) {
        bf16x8 bfrag[8];
#pragma unroll
        for (int kk = 0; kk < 8; ++kk)   // B[k][col]: contiguous 8 k in Gt row
            bfrag[kk] = *(const bf16x8*)(Gt_g + ((j * 16 + lr) << 8) + kk * 32 + lg * 8);
        f32x4 acc0 = {0.f, 0.f, 0.f, 0.f};
        f32x4 acc1 = {0.f, 0.f, 0.f, 0.f};
#pragma unroll
        for (int kk = 0; kk < 8; ++kk) {
            acc0 = __builtin_amdgcn_mfma_f32_16x16x32_bf16(afrag[0][kk], bfrag[kk], acc0, 0, 0, 0);
            acc1 = __builtin_amdgcn_mfma_f32_16x16x32_bf16(afrag[1][kk], bfrag[kk], acc1, 0, 0, 0);
        }
        if (MODE == 0) {
            // C/D layout: col = lane&15, row = (lane>>4)*4 + q
#pragma unroll
            for (int q = 0; q < 4; ++q) {
                int row0 = lg * 4 + q;
                int row1 = 16 + lg * 4 + q;
                int col  = j * 16 + lr;
                *(__hip_bfloat16*)(myM + lds_off(row0, col)) = __float2bfloat16(acc0[q]);
                *(__hip_bfloat16*)(myM + lds_off(row1, col)) = __float2bfloat16(acc1[q]);
            }
        } else if (MODE == 1) {
            Afin[j][0] = acc0;
            Afin[j][1] = acc1;
        } else {
            f32x4 d0 = acc0 - Afin[j][0];
            f32x4 d1 = acc1 - Afin[j][1];
            dsq += d0[0]*d0[0] + d0[1]*d0[1] + d0[2]*d0[2] + d0[3]*d0[3];
            dsq += d1[0]*d1[0] + d1[1]*d1[1] + d1[2]*d1[2] + d1[3]*d1[3];
        }
    }
    if (MODE == 0) {
        // reload A fragments for next step (wave-private rows: no barrier)
#pragma unroll
        for (int rt = 0; rt < 2; ++rt) {
#pragma unroll
            for (int kk = 0; kk < 8; ++kk) {
                int row = rt * 16 + lr;
                afrag[rt][kk] = *(const bf16x8*)(myM + lds_off(row, kk * 32 + lg * 8));
            }
        }
    }
}

// Block = (relation, row-half of 128). 4 waves x 32 rows. Both chains computed
// in-block; chain A final kept in registers, chain B final diffed against it.
__global__ __launch_bounds__(256, 2)
void chain_kernel(const __hip_bfloat16* __restrict__ Gbf,
                  const __hip_bfloat16* __restrict__ Gt,
                  const int* __restrict__ r1,
                  const int* __restrict__ r2,
                  float* __restrict__ part)
{
    __shared__ __align__(16) char Mlds[4][16384];   // 64 KB: 4 waves x 32x256 bf16

    const int tid  = threadIdx.x;
    const int wave = tid >> 6;
    const int lane = tid & 63;
    const int lr   = lane & 15;   // A-row / B-col / D-col within 16-tile
    const int lg   = lane >> 4;   // k-group (8 contiguous k per lane)
    const int r    = blockIdx.x >> 1;
    const int h    = blockIdx.x & 1;
    const int wrow = h * 128 + wave * 32;

    char* myM = Mlds[wave];
    f32x4  Afin[16][2];
    bf16x8 afrag[2][8];
    float  dsq = 0.f;

    { // chain A (r1)
        const int* ix = r1 + r * 6;
        const __hip_bfloat16* g0 = Gbf + (ix[0] << 16);
#pragma unroll
        for (int rt = 0; rt < 2; ++rt)
#pragma unroll
            for (int kk = 0; kk < 8; ++kk)
                afrag[rt][kk] = *(const bf16x8*)(g0 + ((wrow + rt * 16 + lr) << 8) + kk * 32 + lg * 8);
        for (int t = 1; t <= 4; ++t)
            chain_step<0>(afrag, Gt + (ix[t] << 16), myM, Afin, dsq, lr, lg);
        chain_step<1>(afrag, Gt + (ix[5] << 16), myM, Afin, dsq, lr, lg);
    }
    { // chain B (r2)
        const int* ix = r2 + r * 6;
        const __hip_bfloat16* g0 = Gbf + (ix[0] << 16);
#pragma unroll
        for (int rt = 0; rt < 2; ++rt)
#pragma unroll
            for (int kk = 0; kk < 8; ++kk)
                afrag[rt][kk] = *(const bf16x8*)(g0 + ((wrow + rt * 16 + lr) << 8) + kk * 32 + lg * 8);
        for (int t = 1; t <= 4; ++t)
            chain_step<0>(afrag, Gt + (ix[t] << 16), myM, Afin, dsq, lr, lg);
        chain_step<2>(afrag, Gt + (ix[5] << 16), myM, Afin, dsq, lr, lg);
    }

    // reduce dsq: wave shuffle -> LDS (reuse Mlds) -> one atomic per block
#pragma unroll
    for (int off = 32; off > 0; off >>= 1)
        dsq += __shfl_down(dsq, off);
    __syncthreads();                      // waves done with private LDS regions
    float* red = (float*)Mlds;
    if (lane == 0) red[wave] = dsq;
    __syncthreads();
    if (tid == 0) atomicAdd(part + r, red[0] + red[1] + red[2] + red[3]);
}

// ---------------- finish: 512 partial dsq -> sqrt -> mean -----------------------
__global__ void finish_kernel(const float* __restrict__ part, float* __restrict__ out)
{
    int lane = threadIdx.x;   // 64 threads
    float v = 0.f;
#pragma unroll
    for (int i = 0; i < 8; ++i)
        v += sqrtf(part[lane + i * 64]);
#pragma unroll
    for (int off = 32; off > 0; off >>= 1)
        v += __shfl_down(v, off);
    if (lane == 0) out[0] = v * (1.0f / 512.0f);
}

extern "C" void kernel_launch(void* const* d_in, const int* in_sizes, int n_in,
                              void* d_out, int out_size, void* d_ws, size_t ws_size,
                              hipStream_t stream)
{
    const float* G  = (const float*)d_in[0];
    const int*   r1 = (const int*)d_in[1];
    const int*   r2 = (const int*)d_in[2];
    float*       out = (float*)d_out;

    char* ws = (char*)d_ws;
    __hip_bfloat16* Gbf = (__hip_bfloat16*)ws;                  // 4 MB
    __hip_bfloat16* Gt  = (__hip_bfloat16*)(ws + (4u << 20));   // 4 MB
    float*          part = (float*)(ws + (8u << 20));           // 2 KB

    prep_kernel<<<8192, 256, 0, stream>>>(G, Gbf, Gt, part);
    chain_kernel<<<1024, 256, 0, stream>>>(Gbf, Gt, r1, r2, part);
    finish_kernel<<<1, 64, 0, stream>>>(part, out);
}

// Round 2
// 811.937 us; speedup vs baseline: 1.1293x; 1.1293x over previous
//
#include <hip/hip_runtime.h>
#include <hip/hip_bf16.h>

// relationLoss: 1024 chain-products of 6 generator matrices (256x256),
// Frobenius norm of A-B per relation, mean over 512 relations.
// Round 2: spill-free design. Carry lives in 64 VGPRs (bf16 A-fragments),
// chain-A final kept as bf16 fragments (AF, 64 VGPR), G^T staged into LDS
// per 32-col chunk and shared by all 4 waves. 80 KB LDS -> 2 blocks/CU.

#define NREL 512

typedef __attribute__((ext_vector_type(8))) short bf16x8;  // 8 bf16 = 4 VGPRs
typedef __attribute__((ext_vector_type(4))) float f32x4;   // 4 f32 acc

// ---------------- prep: fp32 -> bf16 (row-major + transposed), zero partials ----
__global__ void prep_kernel(const float* __restrict__ G,
                            __hip_bfloat16* __restrict__ Gbf,
                            __hip_bfloat16* __restrict__ Gt,
                            float* __restrict__ part)
{
    int idx = blockIdx.x * 256 + threadIdx.x;      // 0 .. 32*256*256-1
    int g   = idx >> 16;
    int rem = idx & 65535;
    int i   = rem >> 8;      // row (k)
    int j   = rem & 255;     // col
    __hip_bfloat16 h = __float2bfloat16(G[idx]);
    Gbf[idx] = h;                                  // row-major
    Gt[(g << 16) + (j << 8) + i] = h;              // Gt[g][col][k]
    if (idx < NREL) part[idx] = 0.0f;
}

// M-buffer LDS offset (row-major 32x256 bf16, row stride 512B) with the
// round-1-proven XOR swizzle: b128 column-ish reads become conflict-light.
__device__ __forceinline__ int m_off(int row, int col)
{
    return ((row << 9) + (col << 1)) ^ ((row & 7) << 4);
}

__device__ __forceinline__ float b2f(short s)
{
    union { float f; unsigned u; } v;
    v.u = ((unsigned)(unsigned short)s) << 16;
    return v.f;
}

// Block = (relation, row-half of 128). 4 waves x 32 rows, both chains in-block.
// Per step: 8 chunks of G^T (32 cols x 256 k = 16 KB) staged to LDS, consumed
// by all 4 waves; per-wave M buffer holds the new carry for the step-end
// fragment reload. Chain A final kept as bf16 fragments in AF registers.
__global__ __launch_bounds__(256, 2)
void chain_kernel(const __hip_bfloat16* __restrict__ Gbf,
                  const __hip_bfloat16* __restrict__ Gt,
                  const int* __restrict__ r1,
                  const int* __restrict__ r2,
                  float* __restrict__ part)
{
    __shared__ __align__(16) char Gs[16384];       // staged G^T chunk (shared)
    __shared__ __align__(16) char M[4][16384];     // per-wave carry buffers

    const int tid  = threadIdx.x;
    const int wave = tid >> 6;
    const int lane = tid & 63;
    const int lr   = lane & 15;    // A-row / B-col / D-col within 16-tile
    const int lg   = lane >> 4;    // k-group (8 contiguous k per lane)
    const int r    = blockIdx.x >> 1;
    const int h    = blockIdx.x & 1;
    const int wrow = h * 128 + wave * 32;

    char* myM = M[wave];

    bf16x8 cur[2][8];   // carry: 32 rows x 256 cols bf16, A-fragment layout
    bf16x8 AF[2][8];    // chain-A final (bf16 fragments)
    float  dsq = 0.f;

#pragma unroll
    for (int ch = 0; ch < 2; ++ch) {               // ch compile-time (unrolled)
        const int* ix = (ch == 0 ? r1 : r2) + r * 6;

        // init carry = rows of G[ix[0]] (row-major, coalesced b128 loads)
        const __hip_bfloat16* g0 = Gbf + (ix[0] << 16);
#pragma unroll
        for (int rt = 0; rt < 2; ++rt)
#pragma unroll
            for (int kk = 0; kk < 8; ++kk)
                cur[rt][kk] = *(const bf16x8*)(g0 + ((wrow + rt * 16 + lr) << 8) + kk * 32 + lg * 8);

        for (int t = 1; t <= 5; ++t) {
            const __hip_bfloat16* gt = Gt + (ix[t] << 16);

            for (int jc = 0; jc < 8; ++jc) {
                __syncthreads();   // all waves done reading Gs (prev chunk)

                // ---- stage chunk jc: 16 KB, 4 global_load_lds x16B per thread.
                // LDS dest is linear (wave-uniform base + lane*16); the k-slot
                // rotation pi(c,s) = (s+2c)&31 is applied on the GLOBAL source
                // so the swizzled read below sees consistent data (rule 21).
#pragma unroll
                for (int i = 0; i < 4; ++i) {
                    int c  = wave * 8 + i * 2 + (lane >> 5);   // chunk-local col
                    int s  = lane & 31;                        // physical slot
                    int ks = (s - 2 * c) & 31;                 // source k-slot
                    const __hip_bfloat16* src = gt + ((jc * 32 + c) << 8) + ks * 8;
                    char* dst = Gs + wave * 4096 + i * 1024;   // wave-uniform
                    __builtin_amdgcn_global_load_lds(
                        (const __attribute__((address_space(1))) void*)src,
                        (__attribute__((address_space(3))) void*)dst, 16, 0, 0);
                }
                __syncthreads();   // implicit vmcnt(0): staged data visible

                // ---- compute: 32 cols of M_new for this wave's 32 rows
#pragma unroll
                for (int jl = 0; jl < 2; ++jl) {
                    int cl = jl * 16 + lr;                     // chunk-local col
                    f32x4 a0 = {0.f, 0.f, 0.f, 0.f};
                    f32x4 a1 = {0.f, 0.f, 0.f, 0.f};
#pragma unroll
                    for (int kk = 0; kk < 8; ++kk) {
                        int slot = (kk * 4 + lg + 2 * cl) & 31;
                        bf16x8 b = *(const bf16x8*)(Gs + cl * 512 + slot * 16);
                        a0 = __builtin_amdgcn_mfma_f32_16x16x32_bf16(cur[0][kk], b, a0, 0, 0, 0);
                        a1 = __builtin_amdgcn_mfma_f32_16x16x32_bf16(cur[1][kk], b, a1, 0, 0, 0);
                    }
                    // C/D layout: col = lane&15, row = (lane>>4)*4 + q
                    int colb = jc * 32 + cl;
#pragma unroll
                    for (int q = 0; q < 4; ++q) {
                        int row0 = lg * 4 + q;
                        int row1 = 16 + lg * 4 + q;
                        *(__hip_bfloat16*)(myM + m_off(row0, colb)) = __float2bfloat16(a0[q]);
                        *(__hip_bfloat16*)(myM + m_off(row1, colb)) = __float2bfloat16(a1[q]);
                    }
                }
            }

            // ---- end of step: reload carry fragments from wave-private M
            if (t < 5) {
#pragma unroll
                for (int rt = 0; rt < 2; ++rt)
#pragma unroll
                    for (int kk = 0; kk < 8; ++kk)
                        cur[rt][kk] = *(const bf16x8*)(myM + m_off(rt * 16 + lr, kk * 32 + lg * 8));
            } else {
#pragma unroll
                for (int rt = 0; rt < 2; ++rt)
#pragma unroll
                    for (int kk = 0; kk < 8; ++kk) {
                        bf16x8 v = *(const bf16x8*)(myM + m_off(rt * 16 + lr, kk * 32 + lg * 8));
                        if (ch == 0) {
                            AF[rt][kk] = v;            // keep chain-A final
                        } else {
#pragma unroll
                            for (int e = 0; e < 8; ++e) {
                                float d = b2f(v[e]) - b2f(AF[rt][kk][e]);
                                dsq += d * d;
                            }
                        }
                    }
            }
        }
    }

    // reduce dsq: wave shuffle -> LDS -> one atomic per block
#pragma unroll
    for (int off = 32; off > 0; off >>= 1)
        dsq += __shfl_down(dsq, off);
    __syncthreads();
    float* red = (float*)Gs;
    if (lane == 0) red[wave] = dsq;
    __syncthreads();
    if (tid == 0) atomicAdd(part + r, red[0] + red[1] + red[2] + red[3]);
}

// ---------------- finish: 512 partial dsq -> sqrt -> mean -----------------------
__global__ void finish_kernel(const float* __restrict__ part, float* __restrict__ out)
{
    int lane = threadIdx.x;   // 64 threads
    float v = 0.f;
#pragma unroll
    for (int i = 0; i < 8; ++i)
        v += sqrtf(part[lane + i * 64]);
#pragma unroll
    for (int off = 32; off > 0; off >>= 1)
        v += __shfl_down(v, off);
    if (lane == 0) out[0] = v * (1.0f / 512.0f);
}

extern "C" void kernel_launch(void* const* d_in, const int* in_sizes, int n_in,
                              void* d_out, int out_size, void* d_ws, size_t ws_size,
                              hipStream_t stream)
{
    const float* G   = (const float*)d_in[0];
    const int*   r1  = (const int*)d_in[1];
    const int*   r2  = (const int*)d_in[2];
    float*       out = (float*)d_out;

    char* ws = (char*)d_ws;
    __hip_bfloat16* Gbf  = (__hip_bfloat16*)ws;                  // 4 MB
    __hip_bfloat16* Gt   = (__hip_bfloat16*)(ws + (4u << 20));   // 4 MB
    float*          part = (float*)(ws + (8u << 20));            // 2 KB

    prep_kernel<<<8192, 256, 0, stream>>>(G, Gbf, Gt, part);
    chain_kernel<<<1024, 256, 0, stream>>>(Gbf, Gt, r1, r2, part);
    finish_kernel<<<1, 64, 0, stream>>>(part, out);
}

// Round 3
// 453.191 us; speedup vs baseline: 2.0233x; 1.7916x over previous
//
#include <hip/hip_runtime.h>
#include <hip/hip_bf16.h>

// relationLoss round 3: one 512-thread block per relation (8 waves x 32 rows),
// chains A/B interleaved (no AF spill), double-buffered G^T staging with
// counted vmcnt + raw s_barrier (m201 pattern), diff-on-the-fly at step 5.

#define NREL 512

typedef __attribute__((ext_vector_type(8))) short bf16x8;  // 8 bf16 = 4 VGPRs
typedef __attribute__((ext_vector_type(4))) float f32x4;

// ---------------- prep: fp32 -> bf16 (row-major + transposed) ----------------
__global__ void prep_kernel(const float* __restrict__ G,
                            __hip_bfloat16* __restrict__ Gbf,
                            __hip_bfloat16* __restrict__ Gt,
                            float* __restrict__ part)
{
    int idx = blockIdx.x * 256 + threadIdx.x;      // 0 .. 32*256*256-1
    int g   = idx >> 16;
    int rem = idx & 65535;
    int i   = rem >> 8;      // row (k)
    int j   = rem & 255;     // col
    __hip_bfloat16 h = __float2bfloat16(G[idx]);
    Gbf[idx] = h;                                  // row-major
    Gt[(g << 16) + (j << 8) + i] = h;              // Gt[g][col][k]
    if (idx < NREL) part[idx] = 0.0f;
}

// M-buffer swizzle (row-major 32x256 bf16): spreads the 512B row stride.
__device__ __forceinline__ int m_off(int row, int col)
{
    return ((row << 9) + (col << 1)) ^ ((row & 7) << 4);
}

#define WAITVM(N) asm volatile("s_waitcnt vmcnt(" #N ")" ::: "memory")
#define BAR() do { asm volatile("" ::: "memory"); \
                   __builtin_amdgcn_s_barrier();  \
                   asm volatile("" ::: "memory"); } while (0)

__global__ __launch_bounds__(512, 2)
void chain_kernel(const __hip_bfloat16* __restrict__ Gbf,
                  const __hip_bfloat16* __restrict__ Gt,
                  const int* __restrict__ r1,
                  const int* __restrict__ r2,
                  float* __restrict__ part)
{
    __shared__ __align__(16) char Gs[2][16384];    // double-buffered G^T chunk
    __shared__ __align__(16) char M[8][16384];     // per-wave carry transpose buf

    const int tid  = threadIdx.x;
    const int wave = tid >> 6;
    const int lane = tid & 63;
    const int lr   = lane & 15;    // A-row / B-col within 16-tile
    const int lg   = lane >> 4;    // k-group (8 contiguous k)
    const int r    = blockIdx.x;

    char* myM = M[wave];
    bf16x8 curA[2][8], curB[2][8];   // carries: 32 rows x 256 cols, A-frag layout
    float  dsq = 0.f;

    // ---- stage one 16KB chunk (32 cols x 256 k) of G^T; k-slot rotation
    // pi(c,s)=(s+2c)&31 applied on the GLOBAL source (LDS dest linear).
    auto stage = [&](const __hip_bfloat16* gt, int jc, int buf) {
#pragma unroll
        for (int i = 0; i < 2; ++i) {
            int c  = (wave * 2 + i) * 2 + (lane >> 5);
            int s  = lane & 31;
            int ks = (s - 2 * c) & 31;
            const __hip_bfloat16* src = gt + ((jc * 32 + c) << 8) + ks * 8;
            __builtin_amdgcn_global_load_lds(
                (const __attribute__((address_space(1))) void*)src,
                (__attribute__((address_space(3))) void*)(&Gs[buf][(wave * 2 + i) * 1024]),
                16, 0, 0);
        }
    };

    // ---- one chunk of one chain step: 32 cols of M_new, write to wave M buf
    auto computeStep = [&](bf16x8 (&cur)[2][8], int jc, int buf) {
        const char* gs = Gs[buf];
#pragma unroll
        for (int jl = 0; jl < 2; ++jl) {
            int cl = jl * 16 + lr;
            f32x4 a0 = {0.f, 0.f, 0.f, 0.f};
            f32x4 a1 = {0.f, 0.f, 0.f, 0.f};
#pragma unroll
            for (int kk = 0; kk < 8; ++kk) {
                int slot = (kk * 4 + lg + 2 * cl) & 31;
                bf16x8 b = *(const bf16x8*)(gs + cl * 512 + slot * 16);
                a0 = __builtin_amdgcn_mfma_f32_16x16x32_bf16(cur[0][kk], b, a0, 0, 0, 0);
                a1 = __builtin_amdgcn_mfma_f32_16x16x32_bf16(cur[1][kk], b, a1, 0, 0, 0);
            }
            int colb = jc * 32 + cl;
#pragma unroll
            for (int q = 0; q < 4; ++q) {   // C/D: col=lane&15, row=(lane>>4)*4+q
                *(__hip_bfloat16*)(myM + m_off(lg * 4 + q, colb))      = __float2bfloat16(a0[q]);
                *(__hip_bfloat16*)(myM + m_off(16 + lg * 4 + q, colb)) = __float2bfloat16(a1[q]);
            }
        }
    };

    auto reload = [&](bf16x8 (&cur)[2][8]) {
#pragma unroll
        for (int rt = 0; rt < 2; ++rt)
#pragma unroll
            for (int kk = 0; kk < 8; ++kk)
                cur[rt][kk] = *(const bf16x8*)(myM + m_off(rt * 16 + lr, kk * 32 + lg * 8));
    };

    // ---- t=0 init: carry = rows of G[idx0] (row-major b128 loads)
    {
        const __hip_bfloat16* a0p = Gbf + (r1[r * 6] << 16);
        const __hip_bfloat16* b0p = Gbf + (r2[r * 6] << 16);
        int wrow = wave * 32;
#pragma unroll
        for (int rt = 0; rt < 2; ++rt)
#pragma unroll
            for (int kk = 0; kk < 8; ++kk) {
                int ro = (wrow + rt * 16 + lr) << 8;
                curA[rt][kk] = *(const bf16x8*)(a0p + ro + kk * 32 + lg * 8);
                curB[rt][kk] = *(const bf16x8*)(b0p + ro + kk * 32 + lg * 8);
            }
    }

    // ---- steps 1..4: per step, chunks 0..7 chain A then 0..7 chain B,
    // pipelined staging one chunk ahead, two raw barriers per chunk.
#pragma unroll 1
    for (int t = 1; t <= 4; ++t) {
        const __hip_bfloat16* gA = Gt + (r1[r * 6 + t] << 16);
        const __hip_bfloat16* gB = Gt + (r2[r * 6 + t] << 16);
        stage(gA, 0, 0);                       // prologue
#pragma unroll
        for (int u = 0; u < 16; ++u) {
            const int buf = u & 1;
            if (u < 15) {
                stage((u + 1 < 8) ? gA : gB, (u + 1) & 7, buf ^ 1);
                WAITVM(2);                     // my chunk-u loads done; u+1 in flight
            } else {
                WAITVM(0);
            }
            BAR();                             // B1: buf[u&1] fully staged
            if (u < 8) computeStep(curA, u, buf);
            else       computeStep(curB, u & 7, buf);
            if (u == 7)  reload(curA);         // wave-private M: no barrier needed
            if (u == 15) reload(curB);
            BAR();                             // B2: all waves done reading buf[u&1]
        }
    }

    // ---- step 5: alternate A/B per chunk, diff in fp32 registers on the fly.
    {
        const __hip_bfloat16* gA = Gt + (r1[r * 6 + 5] << 16);
        const __hip_bfloat16* gB = Gt + (r2[r * 6 + 5] << 16);
        f32x4 accA[2][2];
        stage(gA, 0, 0);
#pragma unroll
        for (int u = 0; u < 16; ++u) {
            const int buf = u & 1;
            const int jc  = u >> 1;
            if (u < 15) {
                stage((u & 1) ? gB : gA, (u + 1) >> 1, buf ^ 1);
                WAITVM(2);
            } else {
                WAITVM(0);
            }
            BAR();
            const char* gs = Gs[buf];
            if ((u & 1) == 0) {   // chain A final chunk -> keep in accA (fp32)
#pragma unroll
                for (int jl = 0; jl < 2; ++jl) {
                    int cl = jl * 16 + lr;
                    f32x4 a0 = {0.f, 0.f, 0.f, 0.f};
                    f32x4 a1 = {0.f, 0.f, 0.f, 0.f};
#pragma unroll
                    for (int kk = 0; kk < 8; ++kk) {
                        int slot = (kk * 4 + lg + 2 * cl) & 31;
                        bf16x8 b = *(const bf16x8*)(gs + cl * 512 + slot * 16);
                        a0 = __builtin_amdgcn_mfma_f32_16x16x32_bf16(curA[0][kk], b, a0, 0, 0, 0);
                        a1 = __builtin_amdgcn_mfma_f32_16x16x32_bf16(curA[1][kk], b, a1, 0, 0, 0);
                    }
                    accA[jl][0] = a0;
                    accA[jl][1] = a1;
                }
            } else {              // chain B final chunk -> diff vs accA
#pragma unroll
                for (int jl = 0; jl < 2; ++jl) {
                    int cl = jl * 16 + lr;
                    f32x4 a0 = {0.f, 0.f, 0.f, 0.f};
                    f32x4 a1 = {0.f, 0.f, 0.f, 0.f};
#pragma unroll
                    for (int kk = 0; kk < 8; ++kk) {
                        int slot = (kk * 4 + lg + 2 * cl) & 31;
                        bf16x8 b = *(const bf16x8*)(gs + cl * 512 + slot * 16);
                        a0 = __builtin_amdgcn_mfma_f32_16x16x32_bf16(curB[0][kk], b, a0, 0, 0, 0);
                        a1 = __builtin_amdgcn_mfma_f32_16x16x32_bf16(curB[1][kk], b, a1, 0, 0, 0);
                    }
                    f32x4 d0 = a0 - accA[jl][0];
                    f32x4 d1 = a1 - accA[jl][1];
                    dsq += d0[0]*d0[0] + d0[1]*d0[1] + d0[2]*d0[2] + d0[3]*d0[3];
                    dsq += d1[0]*d1[0] + d1[1]*d1[1] + d1[2]*d1[2] + d1[3]*d1[3];
                }
            }
            BAR();
        }
    }

    // ---- reduce dsq over block, one store per relation
#pragma unroll
    for (int off = 32; off > 0; off >>= 1)
        dsq += __shfl_down(dsq, off);
    __syncthreads();
    float* red = (float*)Gs;
    if (lane == 0) red[wave] = dsq;
    __syncthreads();
    if (tid == 0) {
        float s = 0.f;
#pragma unroll
        for (int w = 0; w < 8; ++w) s += red[w];
        part[r] = s;
    }
}

// ---------------- finish: 512 partial dsq -> sqrt -> mean --------------------
__global__ void finish_kernel(const float* __restrict__ part, float* __restrict__ out)
{
    int lane = threadIdx.x;   // 64 threads
    float v = 0.f;
#pragma unroll
    for (int i = 0; i < 8; ++i)
        v += sqrtf(part[lane + i * 64]);
#pragma unroll
    for (int off = 32; off > 0; off >>= 1)
        v += __shfl_down(v, off);
    if (lane == 0) out[0] = v * (1.0f / 512.0f);
}

extern "C" void kernel_launch(void* const* d_in, const int* in_sizes, int n_in,
                              void* d_out, int out_size, void* d_ws, size_t ws_size,
                              hipStream_t stream)
{
    const float* G   = (const float*)d_in[0];
    const int*   r1  = (const int*)d_in[1];
    const int*   r2  = (const int*)d_in[2];
    float*       out = (float*)d_out;

    char* ws = (char*)d_ws;
    __hip_bfloat16* Gbf  = (__hip_bfloat16*)ws;                  // 4 MB
    __hip_bfloat16* Gt   = (__hip_bfloat16*)(ws + (4u << 20));   // 4 MB
    float*          part = (float*)(ws + (8u << 20));            // 2 KB

    prep_kernel<<<8192, 256, 0, stream>>>(G, Gbf, Gt, part);
    chain_kernel<<<NREL, 512, 0, stream>>>(Gbf, Gt, r1, r2, part);
    finish_kernel<<<1, 64, 0, stream>>>(part, out);
}

// Round 7
// 323.258 us; speedup vs baseline: 2.8365x; 1.4019x over previous
//
#include <hip/hip_runtime.h>
#include <hip/hip_bf16.h>

// relationLoss round 7: back to the round-3-VALIDATED component set.
// M*G recurrence, carry as A-operand fragments. 8 waves x 16 rows, 512 thr,
// TWO blocks per relation (grid 1024). Chains sequential; chain-A final kept
// as packed bf16 in 32 registers (AF, static indices). LDS = 80 KB
// (M 8x8KB + Gs 16KB single buffer) -> 2 blocks/CU; spill-free at <=128 VGPR.

#define NREL 512

typedef __attribute__((ext_vector_type(8))) short bf16x8;  // 8 bf16 = 4 VGPRs
typedef __attribute__((ext_vector_type(4))) float f32x4;

static __device__ __forceinline__ float ubits(unsigned u)
{
    union { unsigned u; float f; } v; v.u = u; return v.f;
}
static __device__ __forceinline__ unsigned f2bu(float f)
{
    union { __hip_bfloat16 h; unsigned short s; } v;
    v.h = __float2bfloat16(f);
    return (unsigned)v.s;
}

// ---------------- prep (round-1 validated): fp32 -> bf16 row-major + T -------
__global__ void prep_kernel(const float* __restrict__ G,
                            __hip_bfloat16* __restrict__ Gbf,
                            __hip_bfloat16* __restrict__ Gt,
                            float* __restrict__ part)
{
    int idx = blockIdx.x * 256 + threadIdx.x;      // 0 .. 32*256*256-1
    int g   = idx >> 16;
    int rem = idx & 65535;
    int i   = rem >> 8;      // row (k)
    int j   = rem & 255;     // col
    __hip_bfloat16 h = __float2bfloat16(G[idx]);
    Gbf[idx] = h;                                  // row-major
    Gt[(g << 16) + (j << 8) + i] = h;              // Gt[g][col][k]
    if (idx < NREL) part[idx] = 0.0f;
}

// M-buffer swizzle (16 rows x 256 cols bf16, row stride 512B) — r1/r3 validated
__device__ __forceinline__ int m_off(int row, int col)
{
    return ((row << 9) + (col << 1)) ^ ((row & 7) << 4);
}

// ---- stage one 16KB chunk (32 G^T rows x 256 k); byte-verified vs round 3.
// Physical slot ss of row sr holds source octet (ss - 2*sr) & 31.
static __device__ __forceinline__
void stageChunk(const __hip_bfloat16* __restrict__ gm, int jc, char* dstbuf,
                int tid, int wave)
{
    const int sr0 = tid >> 5, ss = tid & 31;
#pragma unroll
    for (int i = 0; i < 2; ++i) {
        int sr = i * 16 + sr0;
        int ks = (ss - 2 * sr) & 31;
        const __hip_bfloat16* src = gm + jc * 8192 + sr * 256 + ks * 8;
        char* dst = dstbuf + i * 8192 + wave * 1024;   // wave-uniform
        __builtin_amdgcn_global_load_lds(
            (const __attribute__((address_space(1))) void*)src,
            (__attribute__((address_space(3))) void*)dst, 16, 0, 0);
    }
}

// ---- one chain substep (one matrix, 8 chunks). Round-3-validated math.
// MODE 0: write M_new to wave-private M, reload carry at end.
// MODE 1: save final-A packed bf16 into AF registers.
// MODE 2: diff vs AF, accumulate dsq.
template<int MODE>
static __device__ __forceinline__
void substep(const __hip_bfloat16* __restrict__ gt, char* __restrict__ Gs,
             char* __restrict__ myM,
             bf16x8 (&cur)[8], unsigned (&AF)[32], float& dsq,
             int tid, int wave, int lr, int lg)
{
#pragma unroll
    for (int jc = 0; jc < 8; ++jc) {       // FULL unroll: AF indices static
        stageChunk(gt, jc, Gs, tid, wave);
        __syncthreads();                   // vmcnt(0)+lgkmcnt(0) drain: resident
#pragma unroll
        for (int jl = 0; jl < 2; ++jl) {
            const int cl = jl * 16 + lr;   // chunk-local G^T row = output col
            f32x4 acc = {0.f, 0.f, 0.f, 0.f};
#pragma unroll
            for (int kk = 0; kk < 8; ++kk) {
                int slot = (4 * kk + lg + 2 * cl) & 31;
                bf16x8 b = *(const bf16x8*)(Gs + cl * 512 + slot * 16);
                acc = __builtin_amdgcn_mfma_f32_16x16x32_bf16(cur[kk], b, acc, 0, 0, 0);
            }
            if (MODE == 0) {
                // C/D: col = lane&15 (=output col cl), row = lg*4+q (wave-local)
                const int colb = jc * 32 + cl;
#pragma unroll
                for (int q = 0; q < 4; ++q)
                    *(unsigned short*)(myM + m_off(lg * 4 + q, colb)) =
                        (unsigned short)f2bu(acc[q]);
            } else if (MODE == 1) {
                AF[(jc * 2 + jl) * 2 + 0] = f2bu(acc[0]) | (f2bu(acc[1]) << 16);
                AF[(jc * 2 + jl) * 2 + 1] = f2bu(acc[2]) | (f2bu(acc[3]) << 16);
            } else {
                unsigned w0 = AF[(jc * 2 + jl) * 2 + 0];
                unsigned w1 = AF[(jc * 2 + jl) * 2 + 1];
                float d0 = acc[0] - ubits(w0 << 16);
                float d1 = acc[1] - ubits(w0 & 0xffff0000u);
                float d2 = acc[2] - ubits(w1 << 16);
                float d3 = acc[3] - ubits(w1 & 0xffff0000u);
                dsq += d0 * d0 + d1 * d1 + d2 * d2 + d3 * d3;
            }
        }
        __syncthreads();                   // all waves done reading Gs
    }
    if (MODE == 0) {
        // reload carry from wave-private M (in-order LDS within wave)
#pragma unroll
        for (int kk = 0; kk < 8; ++kk)
            cur[kk] = *(const bf16x8*)(myM + m_off(lr, kk * 32 + lg * 8));
    }
}

// ---------------- chain kernel: (relation, row-half) per 512-thread block ----
__global__ __launch_bounds__(512, 4)
void chain_kernel(const __hip_bfloat16* __restrict__ Gbf,
                  const __hip_bfloat16* __restrict__ Gt,
                  const int* __restrict__ r1,
                  const int* __restrict__ r2,
                  float* __restrict__ part)
{
    __shared__ __align__(16) char Gs[16384];     // single staged chunk (shared)
    __shared__ __align__(16) char M[8][8192];    // per-wave 16x256 bf16 carry buf

    const int tid  = threadIdx.x;
    const int wave = tid >> 6;
    const int lane = tid & 63;
    const int lr   = lane & 15;
    const int lg   = lane >> 4;
    const int r    = blockIdx.x >> 1;
    const int h    = blockIdx.x & 1;
    const int wrow = h * 128 + wave * 16;        // this wave's 16 owned rows

    const int* iA = r1 + r * 6;
    const int* iB = r2 + r * 6;

    char* myM = M[wave];
    bf16x8   cur[8];                             // carry: 16 rows, A-frag layout
    unsigned AF[32];                             // chain-A final (packed bf16)
    float    dsq = 0.f;

    // ---- chain A: init carry = rows of Gbf[iA[0]] (row-major b128 loads)
    {
        const __hip_bfloat16* g0 = Gbf + (iA[0] << 16);
#pragma unroll
        for (int kk = 0; kk < 8; ++kk)
            cur[kk] = *(const bf16x8*)(g0 + ((wrow + lr) << 8) + kk * 32 + lg * 8);
    }
#pragma unroll 1
    for (int t = 1; t <= 4; ++t)
        substep<0>(Gt + (iA[t] << 16), Gs, myM, cur, AF, dsq, tid, wave, lr, lg);
    substep<1>(Gt + (iA[5] << 16), Gs, myM, cur, AF, dsq, tid, wave, lr, lg);

    // ---- chain B
    {
        const __hip_bfloat16* g0 = Gbf + (iB[0] << 16);
#pragma unroll
        for (int kk = 0; kk < 8; ++kk)
            cur[kk] = *(const bf16x8*)(g0 + ((wrow + lr) << 8) + kk * 32 + lg * 8);
    }
#pragma unroll 1
    for (int t = 1; t <= 4; ++t)
        substep<0>(Gt + (iB[t] << 16), Gs, myM, cur, AF, dsq, tid, wave, lr, lg);
    substep<2>(Gt + (iB[5] << 16), Gs, myM, cur, AF, dsq, tid, wave, lr, lg);

    // ---- reduce dsq: wave shuffle -> LDS -> one atomic per block (2 blk/rel)
#pragma unroll
    for (int off = 32; off > 0; off >>= 1)
        dsq += __shfl_down(dsq, off);
    __syncthreads();
    float* red = (float*)Gs;
    if (lane == 0) red[wave] = dsq;
    __syncthreads();
    if (tid == 0) {
        float s = 0.f;
#pragma unroll
        for (int w = 0; w < 8; ++w) s += red[w];
        atomicAdd(part + r, s);
    }
}

// ---------------- finish: 512 partial dsq -> sqrt -> mean --------------------
__global__ void finish_kernel(const float* __restrict__ part, float* __restrict__ out)
{
    int lane = threadIdx.x;   // 64 threads
    float v = 0.f;
#pragma unroll
    for (int i = 0; i < 8; ++i)
        v += sqrtf(part[lane + i * 64]);
#pragma unroll
    for (int off = 32; off > 0; off >>= 1)
        v += __shfl_down(v, off);
    if (lane == 0) out[0] = v * (1.0f / 512.0f);
}

extern "C" void kernel_launch(void* const* d_in, const int* in_sizes, int n_in,
                              void* d_out, int out_size, void* d_ws, size_t ws_size,
                              hipStream_t stream)
{
    const float* G   = (const float*)d_in[0];
    const int*   r1  = (const int*)d_in[1];
    const int*   r2  = (const int*)d_in[2];
    float*       out = (float*)d_out;

    char* ws = (char*)d_ws;
    __hip_bfloat16* Gbf  = (__hip_bfloat16*)ws;                  // 4 MB
    __hip_bfloat16* Gt   = (__hip_bfloat16*)(ws + (4u << 20));   // 4 MB
    float*          part = (float*)(ws + (8u << 20));            // 2 KB

    prep_kernel<<<8192, 256, 0, stream>>>(G, Gbf, Gt, part);
    chain_kernel<<<1024, 512, 0, stream>>>(Gbf, Gt, r1, r2, part);
    finish_kernel<<<1, 64, 0, stream>>>(part, out);
}

// Round 8
// 283.867 us; speedup vs baseline: 3.2302x; 1.1388x over previous
//
#include <hip/hip_runtime.h>
#include <hip/hip_bf16.h>

// relationLoss round 8: r7-validated components, restructured for LDS-read
// amortization. 8 waves x 32 rows (two 16-row tiles share each B-fragment),
// one 512-thread block per relation. Sequential chains; chain-A final packed
// bf16 in AF registers (static indices). launch_bounds(512,1) -> cap 256 VGPR
// (no spills); LDS = 160 KB (Gs 2x16K double-buffer + M 8x16K).

#define NREL 512

typedef __attribute__((ext_vector_type(8))) short bf16x8;  // 8 bf16 = 4 VGPRs
typedef __attribute__((ext_vector_type(4))) float f32x4;

static __device__ __forceinline__ float ubits(unsigned u)
{
    union { unsigned u; float f; } v; v.u = u; return v.f;
}
static __device__ __forceinline__ unsigned f2bu(float f)
{
    union { __hip_bfloat16 h; unsigned short s; } v;
    v.h = __float2bfloat16(f);
    return (unsigned)v.s;
}

// ---------------- prep (round-1 validated): fp32 -> bf16 row-major + T -------
__global__ void prep_kernel(const float* __restrict__ G,
                            __hip_bfloat16* __restrict__ Gbf,
                            __hip_bfloat16* __restrict__ Gt,
                            float* __restrict__ part)
{
    int idx = blockIdx.x * 256 + threadIdx.x;      // 0 .. 32*256*256-1
    int g   = idx >> 16;
    int rem = idx & 65535;
    int i   = rem >> 8;      // row (k)
    int j   = rem & 255;     // col
    __hip_bfloat16 h = __float2bfloat16(G[idx]);
    Gbf[idx] = h;                                  // row-major
    Gt[(g << 16) + (j << 8) + i] = h;              // Gt[g][col][k]
    if (idx < NREL) part[idx] = 0.0f;
}

// M-buffer swizzle (32 rows x 256 cols bf16, row stride 512B) — r1/r3 validated
__device__ __forceinline__ int m_off(int row, int col)
{
    return ((row << 9) + (col << 1)) ^ ((row & 7) << 4);
}

// ---- stage one 16KB chunk (32 G^T rows x 256 k); r3/r7-validated.
// Physical slot ss of row sr holds source octet (ss - 2*sr) & 31.
static __device__ __forceinline__
void stageChunk(const __hip_bfloat16* __restrict__ gm, int jc, char* dstbuf,
                int tid, int wave)
{
    const int sr0 = tid >> 5, ss = tid & 31;
#pragma unroll
    for (int i = 0; i < 2; ++i) {
        int sr = i * 16 + sr0;
        int ks = (ss - 2 * sr) & 31;
        const __hip_bfloat16* src = gm + jc * 8192 + sr * 256 + ks * 8;
        char* dst = dstbuf + i * 8192 + wave * 1024;   // wave-uniform
        __builtin_amdgcn_global_load_lds(
            (const __attribute__((address_space(1))) void*)src,
            (__attribute__((address_space(3))) void*)dst, 16, 0, 0);
    }
}

// ---- one chain substep (one matrix, 8 chunks), double-buffered staging.
// MODE 0: write M_new to wave-private M, reload carry at end.
// MODE 1: save final-A packed bf16 into AF registers.
// MODE 2: diff vs AF, accumulate dsq.
template<int MODE>
static __device__ __forceinline__
void substep(const __hip_bfloat16* __restrict__ gt,
             const __hip_bfloat16* __restrict__ gnext,
             char* __restrict__ GsB, char* __restrict__ myM,
             bf16x8 (&cur)[2][8], unsigned (&AF)[2][32], float& dsq,
             int tid, int wave, int lr, int lg)
{
    // precondition: chunk 0 of gt is staged in GsB[jc&1 == 0] and drained.
#pragma unroll
    for (int jc = 0; jc < 8; ++jc) {       // FULL unroll: AF indices static
        const int buf = jc & 1;
        if (jc < 7)      stageChunk(gt,    jc + 1, GsB + (buf ^ 1) * 16384, tid, wave);
        else if (gnext)  stageChunk(gnext, 0,      GsB + (buf ^ 1) * 16384, tid, wave);

        const char* gs = GsB + buf * 16384;
#pragma unroll
        for (int jl = 0; jl < 2; ++jl) {
            const int cl = jl * 16 + lr;   // chunk-local G^T row = output col
            f32x4 acc0 = {0.f, 0.f, 0.f, 0.f};
            f32x4 acc1 = {0.f, 0.f, 0.f, 0.f};
#pragma unroll
            for (int kk = 0; kk < 8; ++kk) {
                int slot = (4 * kk + lg + 2 * cl) & 31;
                bf16x8 b = *(const bf16x8*)(gs + cl * 512 + slot * 16);
                acc0 = __builtin_amdgcn_mfma_f32_16x16x32_bf16(cur[0][kk], b, acc0, 0, 0, 0);
                acc1 = __builtin_amdgcn_mfma_f32_16x16x32_bf16(cur[1][kk], b, acc1, 0, 0, 0);
            }
            if (MODE == 0) {
                // C/D: col = lane&15 (=output col cl), row = lg*4+q per 16-tile
                const int colb = jc * 32 + cl;
#pragma unroll
                for (int q = 0; q < 4; ++q) {
                    *(unsigned short*)(myM + m_off(lg * 4 + q, colb)) =
                        (unsigned short)f2bu(acc0[q]);
                    *(unsigned short*)(myM + m_off(16 + lg * 4 + q, colb)) =
                        (unsigned short)f2bu(acc1[q]);
                }
            } else if (MODE == 1) {
                const int jt = (jc * 2 + jl) * 2;
                AF[0][jt]     = f2bu(acc0[0]) | (f2bu(acc0[1]) << 16);
                AF[0][jt + 1] = f2bu(acc0[2]) | (f2bu(acc0[3]) << 16);
                AF[1][jt]     = f2bu(acc1[0]) | (f2bu(acc1[1]) << 16);
                AF[1][jt + 1] = f2bu(acc1[2]) | (f2bu(acc1[3]) << 16);
            } else {
                const int jt = (jc * 2 + jl) * 2;
                unsigned a0 = AF[0][jt], a1 = AF[0][jt + 1];
                unsigned b0 = AF[1][jt], b1 = AF[1][jt + 1];
                float d0 = acc0[0] - ubits(a0 << 16);
                float d1 = acc0[1] - ubits(a0 & 0xffff0000u);
                float d2 = acc0[2] - ubits(a1 << 16);
                float d3 = acc0[3] - ubits(a1 & 0xffff0000u);
                float e0 = acc1[0] - ubits(b0 << 16);
                float e1 = acc1[1] - ubits(b0 & 0xffff0000u);
                float e2 = acc1[2] - ubits(b1 << 16);
                float e3 = acc1[3] - ubits(b1 & 0xffff0000u);
                dsq += d0*d0 + d1*d1 + d2*d2 + d3*d3;
                dsq += e0*e0 + e1*e1 + e2*e2 + e3*e3;
            }
        }
        __syncthreads();   // drains staging (vmcnt0) + all Gs reads done
    }
    if (MODE == 0) {
        // reload carry from wave-private M (in-order LDS within wave)
#pragma unroll
        for (int rt = 0; rt < 2; ++rt)
#pragma unroll
            for (int kk = 0; kk < 8; ++kk)
                cur[rt][kk] = *(const bf16x8*)(myM + m_off(rt * 16 + lr, kk * 32 + lg * 8));
    }
}

// ---------------- chain kernel: one relation per 512-thread block ------------
__global__ __launch_bounds__(512, 1)
void chain_kernel(const __hip_bfloat16* __restrict__ Gbf,
                  const __hip_bfloat16* __restrict__ Gt,
                  const int* __restrict__ r1,
                  const int* __restrict__ r2,
                  float* __restrict__ part)
{
    __shared__ __align__(16) char Gs[2][16384];  // 32 KB double-buffered stage
    __shared__ __align__(16) char M[8][16384];   // per-wave 32x256 bf16 carry buf

    const int tid  = threadIdx.x;
    const int wave = tid >> 6;
    const int lane = tid & 63;
    const int lr   = lane & 15;
    const int lg   = lane >> 4;
    const int r    = blockIdx.x;
    const int wrow = wave * 32;                  // this wave's 32 owned rows

    const int* iA = r1 + r * 6;
    const int* iB = r2 + r * 6;

    char* GsB = (char*)Gs;
    char* myM = M[wave];
    bf16x8   cur[2][8];                          // carry, A-frag layout (64 VGPR)
    unsigned AF[2][32];                          // chain-A final, packed bf16
    float    dsq = 0.f;

    // ---- chain A: init carry = rows of Gbf[iA[0]] (row-major b128 loads)
    {
        const __hip_bfloat16* g0 = Gbf + (iA[0] << 16);
#pragma unroll
        for (int rt = 0; rt < 2; ++rt)
#pragma unroll
            for (int kk = 0; kk < 8; ++kk)
                cur[rt][kk] = *(const bf16x8*)(g0 + ((wrow + rt * 16 + lr) << 8) + kk * 32 + lg * 8);
    }
    stageChunk(Gt + (iA[1] << 16), 0, GsB, tid, wave);
    __syncthreads();
#pragma unroll 1
    for (int t = 1; t <= 4; ++t)
        substep<0>(Gt + (iA[t] << 16), Gt + (iA[t + 1] << 16), GsB, myM,
                   cur, AF, dsq, tid, wave, lr, lg);
    substep<1>(Gt + (iA[5] << 16), Gt + (iB[1] << 16), GsB, myM,
               cur, AF, dsq, tid, wave, lr, lg);

    // ---- chain B
    {
        const __hip_bfloat16* g0 = Gbf + (iB[0] << 16);
#pragma unroll
        for (int rt = 0; rt < 2; ++rt)
#pragma unroll
            for (int kk = 0; kk < 8; ++kk)
                cur[rt][kk] = *(const bf16x8*)(g0 + ((wrow + rt * 16 + lr) << 8) + kk * 32 + lg * 8);
    }
#pragma unroll 1
    for (int t = 1; t <= 4; ++t)
        substep<0>(Gt + (iB[t] << 16), Gt + (iB[t + 1] << 16), GsB, myM,
                   cur, AF, dsq, tid, wave, lr, lg);
    substep<2>(Gt + (iB[5] << 16), nullptr, GsB, myM,
               cur, AF, dsq, tid, wave, lr, lg);

    // ---- reduce dsq -> part[r] (one block per relation: plain store)
#pragma unroll
    for (int off = 32; off > 0; off >>= 1)
        dsq += __shfl_down(dsq, off);
    __syncthreads();
    float* red = (float*)GsB;
    if (lane == 0) red[wave] = dsq;
    __syncthreads();
    if (tid == 0) {
        float s = 0.f;
#pragma unroll
        for (int w = 0; w < 8; ++w) s += red[w];
        part[r] = s;
    }
}

// ---------------- finish: 512 partial dsq -> sqrt -> mean --------------------
__global__ void finish_kernel(const float* __restrict__ part, float* __restrict__ out)
{
    int lane = threadIdx.x;   // 64 threads
    float v = 0.f;
#pragma unroll
    for (int i = 0; i < 8; ++i)
        v += sqrtf(part[lane + i * 64]);
#pragma unroll
    for (int off = 32; off > 0; off >>= 1)
        v += __shfl_down(v, off);
    if (lane == 0) out[0] = v * (1.0f / 512.0f);
}

extern "C" void kernel_launch(void* const* d_in, const int* in_sizes, int n_in,
                              void* d_out, int out_size, void* d_ws, size_t ws_size,
                              hipStream_t stream)
{
    const float* G   = (const float*)d_in[0];
    const int*   r1  = (const int*)d_in[1];
    const int*   r2  = (const int*)d_in[2];
    float*       out = (float*)d_out;

    char* ws = (char*)d_ws;
    __hip_bfloat16* Gbf  = (__hip_bfloat16*)ws;                  // 4 MB
    __hip_bfloat16* Gt   = (__hip_bfloat16*)(ws + (4u << 20));   // 4 MB
    float*          part = (float*)(ws + (8u << 20));            // 2 KB

    prep_kernel<<<8192, 256, 0, stream>>>(G, Gbf, Gt, part);
    chain_kernel<<<NREL, 512, 0, stream>>>(Gbf, Gt, r1, r2, part);
    finish_kernel<<<1, 64, 0, stream>>>(part, out);
}